// Round 1
// 209.996 us; speedup vs baseline: 1.2282x; 1.2282x over previous
//
#include <hip/hip_runtime.h>
#include <hip/hip_fp16.h>
#include <math.h>

#define H 256
#define W 256
#define HW (H * W)
#define B 2
#define V 3
#define BV (B * V)
#define C 32
#define RADIUS 1.5f
#define TAU 1.0f
#define EPS 1e-8f

#define NPIX (BV * HW)    // 393216 destination pixels (= source points)
#define NBLK (NPIX / 256) // 1536 (divisible by 8 -> bijective XCD swizzle)
#define CAP 16            // fixed slots per dest pixel (mean ~8.2)
#define OVF_CAP 65536     // exact spill list for slots >= CAP (expected empty)

// XCD-aware chunked swizzle: blocks 0..191 -> XCD0, 192..383 -> XCD1, ...
// Neighboring source/dest rows share one XCD's L2 so partial-line bin writes
// merge into full sectors before writeback (and featsT lines get reused).
__device__ __forceinline__ int swizzle_block(int bid) {
    return (bid & 7) * (NBLK / 8) + (bid >> 3);
}

// ---------------------------------------------------------------------------
// Setup: per (b,v) fold the projection chain into one matrix
//   M = K[b] * dst_RT[b] * src_RTinv[b,v] * inv(K[b])
// ---------------------------------------------------------------------------
__global__ void setup_kernel(const float* __restrict__ Kmat,
                             const float* __restrict__ srcRTinv,
                             const float* __restrict__ dstRT,
                             float* __restrict__ Mbuf) {
    int bv = threadIdx.x;
    if (bv >= BV) return;
    int b = bv / V;

    float a[4][8];
    for (int i = 0; i < 4; i++)
        for (int j = 0; j < 4; j++) {
            a[i][j] = Kmat[b * 16 + i * 4 + j];
            a[i][4 + j] = (i == j) ? 1.0f : 0.0f;
        }
    for (int col = 0; col < 4; col++) {
        int piv = col;
        float best = fabsf(a[col][col]);
        for (int r = col + 1; r < 4; r++) {
            float v = fabsf(a[r][col]);
            if (v > best) { best = v; piv = r; }
        }
        if (piv != col) {
            for (int j = 0; j < 8; j++) {
                float t = a[col][j]; a[col][j] = a[piv][j]; a[piv][j] = t;
            }
        }
        float s = 1.0f / a[col][col];
        for (int j = 0; j < 8; j++) a[col][j] *= s;
        for (int r = 0; r < 4; r++) {
            if (r == col) continue;
            float m = a[r][col];
            for (int j = 0; j < 8; j++) a[r][j] -= m * a[col][j];
        }
    }
    float Kinv[16];
    for (int i = 0; i < 4; i++)
        for (int j = 0; j < 4; j++) Kinv[i * 4 + j] = a[i][4 + j];

    float T1[16];
    const float* S = srcRTinv + bv * 16;
    for (int i = 0; i < 4; i++)
        for (int j = 0; j < 4; j++) {
            float acc = 0.0f;
            for (int k = 0; k < 4; k++) acc += S[i * 4 + k] * Kinv[k * 4 + j];
            T1[i * 4 + j] = acc;
        }
    float T2[16];
    const float* D = dstRT + b * 16;
    for (int i = 0; i < 4; i++)
        for (int j = 0; j < 4; j++) {
            float acc = 0.0f;
            for (int k = 0; k < 4; k++) acc += D[i * 4 + k] * T1[k * 4 + j];
            T2[i * 4 + j] = acc;
        }
    const float* Kb = Kmat + b * 16;
    for (int i = 0; i < 4; i++)
        for (int j = 0; j < 4; j++) {
            float acc = 0.0f;
            for (int k = 0; k < 4; k++) acc += Kb[i * 4 + k] * T2[k * 4 + j];
            Mbuf[bv * 16 + i * 4 + j] = acc;
        }
}

// ---------------------------------------------------------------------------
// Tap enumeration: visit every dest pixel q (within-image) whose reference
// weight is > 0: bounds, z>0, dist<RADIUS (d2<RADIUS^2 incl. EPS).
// ---------------------------------------------------------------------------
template <typename F>
__device__ __forceinline__ void for_each_tap(float px, float py, float z, F&& fn) {
    if (!(z > 0.0f)) return;
    float rx = rintf(px), ry = rintf(py);
#pragma unroll
    for (int dy = -1; dy <= 1; dy++) {
#pragma unroll
        for (int dx = -1; dx <= 1; dx++) {
            float ix = rx + (float)dx, iy = ry + (float)dy;
            if (ix >= 0.0f && ix < (float)W && iy >= 0.0f && iy < (float)H) {
                float ddx = ix - px, ddy = iy - py;
                float d2 = ddx * ddx + ddy * ddy + EPS;
                if (d2 < RADIUS * RADIUS) {
                    int q = ((int)iy << 8) | (int)ix;
                    fn(q);
                }
            }
        }
    }
}

// ---------------------------------------------------------------------------
// Phase 1: project + direct-slot fill in ONE pass.
//   slot = atomicAdd(counts[q]); slot < CAP -> bins16[g*CAP+slot] (pixel-major
//   ushort record: all taps of one dest pixel share one 32B line so L2 merges
//   the scattered stores before writeback). No proj4 store: gather recomputes.
// ---------------------------------------------------------------------------
__global__ __launch_bounds__(256) void project_fill_kernel(
    const float* __restrict__ depths, const float* __restrict__ Mbuf,
    int* __restrict__ counts, unsigned short* __restrict__ bins16,
    int* __restrict__ ovf_cnt, int2* __restrict__ ovf) {
    int gid = swizzle_block(blockIdx.x) * 256 + threadIdx.x;
    int bv = gid >> 16;
    int n = gid & (HW - 1);
    int pxi = n & (W - 1);
    int pyi = n >> 8;

    float xn = (float)pxi * (2.0f / (W - 1)) - 1.0f;
    float yn = (float)pyi * (2.0f / (H - 1)) - 1.0f;
    float d = depths[gid];
    const float* M = Mbuf + bv * 16;
    float X = xn * d, Y = yn * d;
    float p0 = M[0] * X + M[1] * Y + M[2] * d + M[3];
    float p1 = M[4] * X + M[5] * Y + M[6] * d + M[7];
    float z  = M[8] * X + M[9] * Y + M[10] * d + M[11];

    bool zpos = z > 0.0f;
    float inv = 1.0f / (z + EPS);
    float xp = zpos ? p0 * inv : -10.0f;
    float yp = zpos ? p1 * inv : -10.0f;
    float px = (xp + 1.0f) * 0.5f * (float)(W - 1);
    float py = (yp + 1.0f) * 0.5f * (float)(H - 1);

    int base = bv << 16;
    for_each_tap(px, py, z, [&](int q) {
        int g = base | q;
        int slot = atomicAdd(&counts[g], 1);
        if (slot < CAP) {
            bins16[(size_t)g * CAP + slot] = (unsigned short)n;
        } else {
            int o = atomicAdd(ovf_cnt, 1);
            if (o < OVF_CAP) ovf[o] = make_int2(g, n);
        }
    });
}

// ---------------------------------------------------------------------------
// Transpose feats (BV,C,HW) fp32 -> featsT (BV,HW,C) fp16: one contiguous
// 64B record per point.
// ---------------------------------------------------------------------------
__global__ __launch_bounds__(256) void transpose_kernel(
    const float* __restrict__ feats, __half* __restrict__ featsT) {
    __shared__ float sm[C][257];
    int blk = blockIdx.x;
    int bv = blk >> 8;
    int n0 = (blk & 255) << 8;
    int tid = threadIdx.x;
    const float* src = feats + (size_t)bv * C * HW + n0;
#pragma unroll
    for (int c = 0; c < C; c++) sm[c][tid] = src[(size_t)c * HW + tid];
    __syncthreads();
    __half* dst = featsT + ((size_t)bv * HW + n0) * C;
#pragma unroll
    for (int pass = 0; pass < 8; pass++) {
        int nl = pass * 32 + (tid >> 3);
        int c4 = (tid & 7) << 2;
        __half2 lo = __floats2half2_rn(sm[c4][nl], sm[c4 + 1][nl]);
        __half2 hi = __floats2half2_rn(sm[c4 + 2][nl], sm[c4 + 3][nl]);
        uint2 pk;
        pk.x = *(unsigned int*)&lo;
        pk.y = *(unsigned int*)&hi;
        *(uint2*)(dst + (size_t)nl * C + c4) = pk;
    }
}

// ---------------------------------------------------------------------------
// Phase 2: gather. One thread per dest pixel. Pixel-major ushort bins: one
// 32B record per thread, loaded as 2x uint4. Projection recomputed from
// depth+M (bit-identical to phase 1, VALU was 2% busy). Overflow entries
// (cnt > CAP) resolved exactly by scanning the spill list (expected empty).
// ---------------------------------------------------------------------------
__global__ __launch_bounds__(256) void gather_kernel(
    const float* __restrict__ depths, const float* __restrict__ Mbuf,
    const __half* __restrict__ featsT, const int* __restrict__ counts,
    const unsigned short* __restrict__ bins16,
    const int* __restrict__ ovf_cnt, const int2* __restrict__ ovf,
    float* __restrict__ out) {
    int gid = swizzle_block(blockIdx.x) * 256 + threadIdx.x;
    int bv = gid >> 16;
    int q = gid & (HW - 1);
    float qx = (float)(q & (W - 1));
    float qy = (float)(q >> 8);

    int cnt = counts[gid];
    int cap = min(cnt, CAP);

    const float* M = Mbuf + bv * 16;
    float m00 = M[0], m01 = M[1], m02 = M[2],  m03 = M[3];
    float m10 = M[4], m11 = M[5], m12 = M[6],  m13 = M[7];
    float m20 = M[8], m21 = M[9], m22 = M[10], m23 = M[11];

    const float* dep = depths + ((size_t)bv << 16);
    const __half* fb = featsT + ((size_t)bv << 16) * C;

    float wsum = 0.0f, zwsum = 0.0f;
    float facc[C];
#pragma unroll
    for (int c = 0; c < C; c++) facc[c] = 0.0f;

    auto accumulate = [&](int n) {
        // recompute projection (bins only contain z>0 points)
        float d = dep[n];
        float xn = (float)(n & (W - 1)) * (2.0f / (W - 1)) - 1.0f;
        float yn = (float)(n >> 8)      * (2.0f / (H - 1)) - 1.0f;
        float X = xn * d, Y = yn * d;
        float p0 = m00 * X + m01 * Y + m02 * d + m03;
        float p1 = m10 * X + m11 * Y + m12 * d + m13;
        float z  = m20 * X + m21 * Y + m22 * d + m23;
        float inv = 1.0f / (z + EPS);
        float px = (p0 * inv + 1.0f) * 0.5f * (float)(W - 1);
        float py = (p1 * inv + 1.0f) * 0.5f * (float)(H - 1);
        float ddx = qx - px, ddy = qy - py;
        float dist = sqrtf(ddx * ddx + ddy * ddy + EPS);
        float wr = fmaxf(0.0f, 1.0f - dist * (1.0f / RADIUS));
        float w = wr * expf(-TAU * z);
        wsum += w;
        zwsum += z * w;
        const uint4* fp = (const uint4*)(fb + (size_t)n * C);
#pragma unroll
        for (int g = 0; g < 4; g++) {
            uint4 v = fp[g];
            const __half2* h2 = (const __half2*)&v;
#pragma unroll
            for (int k = 0; k < 4; k++) {
                float2 f2 = __half22float2(h2[k]);
                facc[g * 8 + 2 * k]     = fmaf(w, f2.x, facc[g * 8 + 2 * k]);
                facc[g * 8 + 2 * k + 1] = fmaf(w, f2.y, facc[g * 8 + 2 * k + 1]);
            }
        }
    };

    // one 32B record per thread, vector-loaded; compile-time slot extraction
    const uint4* bp = (const uint4*)(bins16 + (size_t)gid * CAP);
    uint4 r0 = bp[0];
    uint4 r1 = bp[1];
    auto do2 = [&](unsigned int wv, int j0) {
        if (j0 < cap)     accumulate((int)(wv & 0xffffu));
        if (j0 + 1 < cap) accumulate((int)(wv >> 16));
    };
    do2(r0.x, 0);  do2(r0.y, 2);  do2(r0.z, 4);  do2(r0.w, 6);
    do2(r1.x, 8);  do2(r1.y, 10); do2(r1.z, 12); do2(r1.w, 14);

    if (cnt > CAP) {  // exact spill path; expected never taken
        int oc = min(*ovf_cnt, OVF_CAP);
        for (int i = 0; i < oc; i++) {
            int2 e = ovf[i];
            if (e.x == gid) accumulate(e.y);
        }
    }

    float invw = 1.0f / (wsum + EPS);
    float* ob = out + (size_t)bv * C * HW + q;
#pragma unroll
    for (int c = 0; c < C; c++) ob[(size_t)c * HW] = facc[c] * invw;
    out[(size_t)BV * C * HW + gid] = zwsum * invw;
}

extern "C" void kernel_launch(void* const* d_in, const int* in_sizes, int n_in,
                              void* d_out, int out_size, void* d_ws, size_t ws_size,
                              hipStream_t stream) {
    const float* depths   = (const float*)d_in[0];  // (B,V,1,H,W)
    const float* feats    = (const float*)d_in[1];  // (B,V,C,H,W)
    const float* Kmat     = (const float*)d_in[2];  // (B,4,4)
    const float* srcRTinv = (const float*)d_in[4];  // (B,V,4,4)
    const float* dstRT    = (const float*)d_in[5];  // (B,1,4,4)
    float* out = (float*)d_out;

    // ws layout:
    //   bins16  : CAP*NPIX ushort (pixel-major) 12.58 MB
    //   featsT  : NPIX*C __half                 25.17 MB
    //   counts  : NPIX int + ovf_cnt             1.57 MB (+16B, memset together)
    //   ovf     : OVF_CAP int2                   0.52 MB
    //   Mbuf    : BV*16 float                    tiny
    // total ~39.9 MB (<= 63 MB proven available)
    char* ws = (char*)d_ws;
    size_t off_bins = 0;
    size_t off_featsT = off_bins + (size_t)CAP * NPIX * 2;
    size_t off_counts = off_featsT + (size_t)NPIX * C * 2;
    size_t off_ovfcnt = off_counts + (size_t)NPIX * 4;
    size_t off_ovf = off_ovfcnt + 16;  // keep int2 array 8B-aligned
    size_t off_M = off_ovf + (size_t)OVF_CAP * 8;
    size_t needed = off_M + (size_t)BV * 16 * 4;

    if (ws_size < needed) {
        hipMemsetAsync(d_out, 0, (size_t)out_size * 4, stream);
        return;
    }

    unsigned short* bins16 = (unsigned short*)(ws + off_bins);
    __half* featsT = (__half*)(ws + off_featsT);
    int* counts    = (int*)(ws + off_counts);
    int* ovf_cnt   = (int*)(ws + off_ovfcnt);
    int2* ovf      = (int2*)(ws + off_ovf);
    float* Mbuf    = (float*)(ws + off_M);

    // zero counts + overflow cursor in one memset (adjacent)
    hipMemsetAsync(counts, 0, (size_t)NPIX * 4 + 16, stream);
    setup_kernel<<<1, 64, 0, stream>>>(Kmat, srcRTinv, dstRT, Mbuf);
    project_fill_kernel<<<NBLK, 256, 0, stream>>>(depths, Mbuf, counts, bins16,
                                                  ovf_cnt, ovf);
    transpose_kernel<<<NBLK, 256, 0, stream>>>(feats, featsT);
    gather_kernel<<<NBLK, 256, 0, stream>>>(depths, Mbuf, featsT, counts,
                                            bins16, ovf_cnt, ovf, out);
}

// Round 2
// 197.061 us; speedup vs baseline: 1.3088x; 1.0656x over previous
//
#include <hip/hip_runtime.h>
#include <hip/hip_fp16.h>
#include <math.h>

#define H 256
#define W 256
#define HW (H * W)
#define B 2
#define V 3
#define BV (B * V)
#define C 32
#define RADIUS 1.5f
#define TAU 1.0f
#define EPS 1e-8f

#define NPIX (BV * HW)    // 393216 destination pixels (= source points)
#define NBLK (NPIX / 256) // 1536 (divisible by 8 -> bijective XCD swizzle)

// Cell grid: one bin per ROUNDED projected position, with a 1-pixel halo so
// points rounding to -1 or W/H (which still have in-image taps) are kept.
#define GW 258
#define GH 258
#define NCELL (BV * GH * GW)  // 399384 cells, mean occupancy ~0.91
#define CCAP 8                // slots per cell (Poisson(0.91) tail ~1e-7)
#define OVF_CAP 65536         // exact spill list (expected empty)

// XCD-aware chunked swizzle (NBLK divisible by 8 -> bijective).
__device__ __forceinline__ int swizzle_block(int bid) {
    return (bid & 7) * (NBLK / 8) + (bid >> 3);
}

// ---------------------------------------------------------------------------
// Setup: per (b,v) fold the projection chain into one matrix
//   M = K[b] * dst_RT[b] * src_RTinv[b,v] * inv(K[b])
// ---------------------------------------------------------------------------
__global__ void setup_kernel(const float* __restrict__ Kmat,
                             const float* __restrict__ srcRTinv,
                             const float* __restrict__ dstRT,
                             float* __restrict__ Mbuf) {
    int bv = threadIdx.x;
    if (bv >= BV) return;
    int b = bv / V;

    float a[4][8];
    for (int i = 0; i < 4; i++)
        for (int j = 0; j < 4; j++) {
            a[i][j] = Kmat[b * 16 + i * 4 + j];
            a[i][4 + j] = (i == j) ? 1.0f : 0.0f;
        }
    for (int col = 0; col < 4; col++) {
        int piv = col;
        float best = fabsf(a[col][col]);
        for (int r = col + 1; r < 4; r++) {
            float v = fabsf(a[r][col]);
            if (v > best) { best = v; piv = r; }
        }
        if (piv != col) {
            for (int j = 0; j < 8; j++) {
                float t = a[col][j]; a[col][j] = a[piv][j]; a[piv][j] = t;
            }
        }
        float s = 1.0f / a[col][col];
        for (int j = 0; j < 8; j++) a[col][j] *= s;
        for (int r = 0; r < 4; r++) {
            if (r == col) continue;
            float m = a[r][col];
            for (int j = 0; j < 8; j++) a[r][j] -= m * a[col][j];
        }
    }
    float Kinv[16];
    for (int i = 0; i < 4; i++)
        for (int j = 0; j < 4; j++) Kinv[i * 4 + j] = a[i][4 + j];

    float T1[16];
    const float* S = srcRTinv + bv * 16;
    for (int i = 0; i < 4; i++)
        for (int j = 0; j < 4; j++) {
            float acc = 0.0f;
            for (int k = 0; k < 4; k++) acc += S[i * 4 + k] * Kinv[k * 4 + j];
            T1[i * 4 + j] = acc;
        }
    float T2[16];
    const float* D = dstRT + b * 16;
    for (int i = 0; i < 4; i++)
        for (int j = 0; j < 4; j++) {
            float acc = 0.0f;
            for (int k = 0; k < 4; k++) acc += D[i * 4 + k] * T1[k * 4 + j];
            T2[i * 4 + j] = acc;
        }
    const float* Kb = Kmat + b * 16;
    for (int i = 0; i < 4; i++)
        for (int j = 0; j < 4; j++) {
            float acc = 0.0f;
            for (int k = 0; k < 4; k++) acc += Kb[i * 4 + k] * T2[k * 4 + j];
            Mbuf[bv * 16 + i * 4 + j] = acc;
        }
}

// ---------------------------------------------------------------------------
// Phase 1: project + CELL fill. ONE atomic + ONE 8B store per point
// (9x fewer scatter ops than tap-binning). Entry = {n (as uint bits), depth}
// so gather recomputes the projection bit-identically with zero scattered
// depth reads.
// ---------------------------------------------------------------------------
__global__ __launch_bounds__(256) void project_fill_kernel(
    const float* __restrict__ depths, const float* __restrict__ Mbuf,
    int* __restrict__ counts, float2* __restrict__ cells,
    int* __restrict__ ovf_cnt, int4* __restrict__ ovf) {
    int gid = swizzle_block(blockIdx.x) * 256 + threadIdx.x;
    int bv = gid >> 16;
    int n = gid & (HW - 1);
    int pxi = n & (W - 1);
    int pyi = n >> 8;

    float xn = (float)pxi * (2.0f / (W - 1)) - 1.0f;
    float yn = (float)pyi * (2.0f / (H - 1)) - 1.0f;
    float d = depths[gid];
    const float* M = Mbuf + bv * 16;
    float X = xn * d, Y = yn * d;
    float p0 = M[0] * X + M[1] * Y + M[2] * d + M[3];
    float p1 = M[4] * X + M[5] * Y + M[6] * d + M[7];
    float z  = M[8] * X + M[9] * Y + M[10] * d + M[11];

    if (!(z > 0.0f)) return;  // reference masks z<=0 taps entirely
    float inv = 1.0f / (z + EPS);
    float px = (p0 * inv + 1.0f) * 0.5f * (float)(W - 1);
    float py = (p1 * inv + 1.0f) * 0.5f * (float)(H - 1);
    float rx = rintf(px), ry = rintf(py);
    // points rounding outside the halo have no tap with weight > 0
    if (rx < -1.0f || rx > (float)W || ry < -1.0f || ry > (float)H) return;

    int cell = bv * (GH * GW) + ((int)ry + 1) * GW + ((int)rx + 1);
    int slot = atomicAdd(&counts[cell], 1);
    if (slot < CCAP) {
        float2 e;
        e.x = __uint_as_float((unsigned int)n);
        e.y = d;
        cells[(size_t)cell * CCAP + slot] = e;
    } else {
        int o = atomicAdd(ovf_cnt, 1);
        if (o < OVF_CAP) ovf[o] = make_int4(cell, n, __float_as_int(d), 0);
    }
}

// ---------------------------------------------------------------------------
// Transpose feats (BV,C,HW) fp32 -> featsT (BV,HW,C) fp16: one contiguous
// 64B record per point.
// ---------------------------------------------------------------------------
__global__ __launch_bounds__(256) void transpose_kernel(
    const float* __restrict__ feats, __half* __restrict__ featsT) {
    __shared__ float sm[C][257];
    int blk = blockIdx.x;
    int bv = blk >> 8;
    int n0 = (blk & 255) << 8;
    int tid = threadIdx.x;
    const float* src = feats + (size_t)bv * C * HW + n0;
#pragma unroll
    for (int c = 0; c < C; c++) sm[c][tid] = src[(size_t)c * HW + tid];
    __syncthreads();
    __half* dst = featsT + ((size_t)bv * HW + n0) * C;
#pragma unroll
    for (int pass = 0; pass < 8; pass++) {
        int nl = pass * 32 + (tid >> 3);
        int c4 = (tid & 7) << 2;
        __half2 lo = __floats2half2_rn(sm[c4][nl], sm[c4 + 1][nl]);
        __half2 hi = __floats2half2_rn(sm[c4 + 2][nl], sm[c4 + 3][nl]);
        uint2 pk;
        pk.x = *(unsigned int*)&lo;
        pk.y = *(unsigned int*)&hi;
        *(uint2*)(dst + (size_t)nl * C + c4) = pk;
    }
}

// ---------------------------------------------------------------------------
// Phase 2: gather. One thread per dest pixel q; scan the 3x3 cell
// neighborhood of q on the halo grid. Every tap with weight > 0 has
// rint(p) in q+-1, so this visits exactly the reference tap set.
// Cell reads are a 3-wide stencil (L1/L2 friendly). Overflowing cells
// (cnt > CCAP, expected none) resolved exactly via the spill list.
// ---------------------------------------------------------------------------
__global__ __launch_bounds__(256) void gather_kernel(
    const float* __restrict__ Mbuf, const __half* __restrict__ featsT,
    const int* __restrict__ counts, const float2* __restrict__ cells,
    const int* __restrict__ ovf_cnt, const int4* __restrict__ ovf,
    float* __restrict__ out) {
    int gid = swizzle_block(blockIdx.x) * 256 + threadIdx.x;
    int bv = gid >> 16;
    int q = gid & (HW - 1);
    float qx = (float)(q & (W - 1));
    float qy = (float)(q >> 8);

    const float* M = Mbuf + bv * 16;
    float m00 = M[0], m01 = M[1], m02 = M[2],  m03 = M[3];
    float m10 = M[4], m11 = M[5], m12 = M[6],  m13 = M[7];
    float m20 = M[8], m21 = M[9], m22 = M[10], m23 = M[11];

    const __half* fb = featsT + ((size_t)bv << 16) * C;

    float wsum = 0.0f, zwsum = 0.0f;
    float facc[C];
#pragma unroll
    for (int c = 0; c < C; c++) facc[c] = 0.0f;

    auto accumulate = [&](int n, float d) {
        // recompute projection bit-identically to phase 1 (z>0 guaranteed)
        float xn = (float)(n & (W - 1)) * (2.0f / (W - 1)) - 1.0f;
        float yn = (float)(n >> 8)      * (2.0f / (H - 1)) - 1.0f;
        float X = xn * d, Y = yn * d;
        float p0 = m00 * X + m01 * Y + m02 * d + m03;
        float p1 = m10 * X + m11 * Y + m12 * d + m13;
        float z  = m20 * X + m21 * Y + m22 * d + m23;
        float inv = 1.0f / (z + EPS);
        float px = (p0 * inv + 1.0f) * 0.5f * (float)(W - 1);
        float py = (p1 * inv + 1.0f) * 0.5f * (float)(H - 1);
        float ddx = qx - px, ddy = qy - py;
        float dist = sqrtf(ddx * ddx + ddy * ddy + EPS);
        float wr = fmaxf(0.0f, 1.0f - dist * (1.0f / RADIUS));
        if (wr > 0.0f) {
            float w = wr * expf(-TAU * z);
            wsum += w;
            zwsum += z * w;
            const uint4* fp = (const uint4*)(fb + (size_t)n * C);
#pragma unroll
            for (int g = 0; g < 4; g++) {
                uint4 v = fp[g];
                const __half2* h2 = (const __half2*)&v;
#pragma unroll
                for (int k = 0; k < 4; k++) {
                    float2 f2 = __half22float2(h2[k]);
                    facc[g * 8 + 2 * k]     = fmaf(w, f2.x, facc[g * 8 + 2 * k]);
                    facc[g * 8 + 2 * k + 1] = fmaf(w, f2.y, facc[g * 8 + 2 * k + 1]);
                }
            }
        }
    };

    // cells for rows qy-1..qy+1, cols qx-1..qx+1 -> halo coords qy+dy, qx+dx
    int cbase = bv * (GH * GW);
#pragma unroll
    for (int dy = 0; dy < 3; dy++) {
        int rowbase = cbase + (q / W + dy) * GW + (q & (W - 1));
#pragma unroll
        for (int dx = 0; dx < 3; dx++) {
            int cell = rowbase + dx;
            int cc = counts[cell];
            int m = min(cc, CCAP);
            const float2* e = cells + (size_t)cell * CCAP;
            for (int j = 0; j < m; j++) {
                float2 v = e[j];
                accumulate((int)__float_as_uint(v.x), v.y);
            }
            if (cc > CCAP) {  // exact spill path; expected never taken
                int oc = min(*ovf_cnt, OVF_CAP);
                for (int i = 0; i < oc; i++) {
                    int4 t = ovf[i];
                    if (t.x == cell) accumulate(t.y, __int_as_float(t.z));
                }
            }
        }
    }

    float invw = 1.0f / (wsum + EPS);
    float* ob = out + (size_t)bv * C * HW + q;
#pragma unroll
    for (int c = 0; c < C; c++) ob[(size_t)c * HW] = facc[c] * invw;
    out[(size_t)BV * C * HW + gid] = zwsum * invw;
}

extern "C" void kernel_launch(void* const* d_in, const int* in_sizes, int n_in,
                              void* d_out, int out_size, void* d_ws, size_t ws_size,
                              hipStream_t stream) {
    const float* depths   = (const float*)d_in[0];  // (B,V,1,H,W)
    const float* feats    = (const float*)d_in[1];  // (B,V,C,H,W)
    const float* Kmat     = (const float*)d_in[2];  // (B,4,4)
    const float* srcRTinv = (const float*)d_in[4];  // (B,V,4,4)
    const float* dstRT    = (const float*)d_in[5];  // (B,1,4,4)
    float* out = (float*)d_out;

    // ws layout:
    //   cells   : NCELL*CCAP float2 (8B entries)  25.56 MB
    //   featsT  : NPIX*C __half                   25.17 MB
    //   counts  : NCELL int + ovf_cnt              1.60 MB (+16B, memset together)
    //   ovf     : OVF_CAP int4                     1.05 MB
    //   Mbuf    : BV*16 float                      tiny
    // total ~53.4 MB (<= 63 MB proven available)
    char* ws = (char*)d_ws;
    size_t off_cells = 0;
    size_t off_featsT = off_cells + (size_t)NCELL * CCAP * 8;
    size_t off_counts = off_featsT + (size_t)NPIX * C * 2;
    size_t off_ovfcnt = off_counts + (size_t)NCELL * 4;
    size_t off_ovf = off_ovfcnt + 16;  // keep int4 array 16B-aligned
    size_t off_M = off_ovf + (size_t)OVF_CAP * 16;
    size_t needed = off_M + (size_t)BV * 16 * 4;

    if (ws_size < needed) {
        hipMemsetAsync(d_out, 0, (size_t)out_size * 4, stream);
        return;
    }

    float2* cells  = (float2*)(ws + off_cells);
    __half* featsT = (__half*)(ws + off_featsT);
    int* counts    = (int*)(ws + off_counts);
    int* ovf_cnt   = (int*)(ws + off_ovfcnt);
    int4* ovf      = (int4*)(ws + off_ovf);
    float* Mbuf    = (float*)(ws + off_M);

    // zero counts + overflow cursor in one memset (adjacent)
    hipMemsetAsync(counts, 0, (size_t)NCELL * 4 + 16, stream);
    setup_kernel<<<1, 64, 0, stream>>>(Kmat, srcRTinv, dstRT, Mbuf);
    project_fill_kernel<<<NBLK, 256, 0, stream>>>(depths, Mbuf, counts, cells,
                                                  ovf_cnt, ovf);
    transpose_kernel<<<NBLK, 256, 0, stream>>>(feats, featsT);
    gather_kernel<<<NBLK, 256, 0, stream>>>(Mbuf, featsT, counts, cells,
                                            ovf_cnt, ovf, out);
}